// Round 4
// baseline (688.172 us; speedup 1.0000x reference)
//
#include <hip/hip_runtime.h>
#include <hip/hip_fp16.h>
#include <cmath>

#define NN 20000
#define FF 128
#define EE 32768
#define RR 8

#define OUT_X (NN*FF)            // 2,560,000
#define OUT_M (NN*FF + NN*12)    // 2,800,000

typedef _Float16 half8 __attribute__((ext_vector_type(8)));
typedef float f32x4 __attribute__((ext_vector_type(4)));

#define MFMA16(a,b,c) __builtin_amdgcn_mfma_f32_16x16x32_f16(a, b, c, 0, 0, 0)

__device__ __forceinline__ float silu_f(float x) {
    return x / (1.0f + __expf(-x));
}
__device__ __forceinline__ unsigned short f2h(float x) {
    _Float16 h = (_Float16)x;
    return __builtin_bit_cast(unsigned short, h);
}
__device__ __forceinline__ float h2f(unsigned short u) {
    return (float)__builtin_bit_cast(_Float16, u);
}

__device__ __forceinline__ void seg_atomic(unsigned short* p, unsigned bits) {
#if __has_builtin(__builtin_amdgcn_flat_atomic_fadd_v2f16)
    typedef _Float16 v2h __attribute__((ext_vector_type(2)));
    v2h v = __builtin_bit_cast(v2h, bits);
    __builtin_amdgcn_flat_atomic_fadd_v2f16((v2h*)p, v);
#else
    __half2 v = __builtin_bit_cast(__half2, bits);
    unsafeAtomicAdd((__half2*)p, v);
#endif
}

__device__ __forceinline__ void zero8(f32x4 acc[8]) {
#pragma unroll
    for (int m = 0; m < 8; m++) acc[m] = (f32x4)0.f;
}

// one K-chunk (32) vs this wave's single n-tile; A gathered from global rows
__device__ __forceinline__ void gchunk8(const unsigned short* __restrict__ Bp, int c,
                                        const unsigned short* __restrict__ src,
                                        const int* nodes, int coff,
                                        int wid, int q, int n16, f32x4 acc[8])
{
    half8 b = *(const half8*)(Bp + (size_t)((c * 8 + wid) * 4 + q) * 128 + n16 * 8);
#pragma unroll
    for (int m = 0; m < 8; m++) {
        half8 a = *(const half8*)(src + (size_t)nodes[m] * 128 + coff + q * 8);
        acc[m] = MFMA16(a, b, acc[m]);
    }
}

// A from LDS tile (128 x NCH*32, stride 136)
template<int NCH>
__device__ __forceinline__ void gemm_lds8(const unsigned short* __restrict__ Bp,
                                          const unsigned short* sA,
                                          int wid, int q, int n16, f32x4 acc[8])
{
#pragma unroll
    for (int c = 0; c < NCH; c++) {
        half8 b = *(const half8*)(Bp + (size_t)((c * 8 + wid) * 4 + q) * 128 + n16 * 8);
#pragma unroll
        for (int m = 0; m < 8; m++) {
            half8 a = *(const half8*)(sA + (m * 16 + n16) * 136 + c * 32 + q * 8);
            acc[m] = MFMA16(a, b, acc[m]);
        }
    }
}

// C/D layout: col = lane&15 (tile col), row = (lane>>4)*4 + reg
__device__ __forceinline__ void store_act8(f32x4 acc[8], const float* __restrict__ bias,
                                           unsigned short* sOut, int n16, int q, int wid,
                                           bool dosilu)
{
    const int n = wid * 16 + n16;
    const float bb = bias[n];
#pragma unroll
    for (int m = 0; m < 8; m++)
#pragma unroll
        for (int rr = 0; rr < 4; rr++) {
            float v = acc[m][rr] + bb;
            if (dosilu) v = silu_f(v);
            sOut[(m * 16 + q * 4 + rr) * 136 + n] = f2h(v);
        }
}

// ============ prep: h -> f16 ============
__global__ __launch_bounds__(256) void k_cvt_h(const float* __restrict__ h,
                                               unsigned short* __restrict__ h_bf)
{
    const int i = (blockIdx.x * 256 + threadIdx.x) * 4;
    float4 v = *(const float4*)(h + i);
    unsigned short u[4] = { f2h(v.x), f2h(v.y), f2h(v.z), f2h(v.w) };
    *(uint2*)(h_bf + i) = *(const uint2*)u;
}

// ============ fused weight pack (all weights, one launch) ============
__device__ __forceinline__ void pack_block(const float* __restrict__ Wb,
                                           unsigned short* __restrict__ db,
                                           int K, int remap, int blk)
{
    const int p = blk * 256 + threadIdx.x;
    const int j = p & 7, n16 = (p >> 3) & 15, q = (p >> 7) & 3, t = (p >> 9) & 7, c = p >> 12;
    int k = c * 32 + q * 8 + j;
    if (remap) k = (k < 128) ? k : (k < 256) ? (k + 1) : (k == 256 ? 128 : K);
    const int n = t * 16 + n16;
    db[p] = f2h((k < K) ? Wb[(size_t)k * 128 + n] : 0.f);
}

__global__ __launch_bounds__(256) void k_pack_all(
    const float* __restrict__ Wm1, const float* __restrict__ Wm2,
    const float* __restrict__ Wn1, const float* __restrict__ Wn2,
    const float* __restrict__ We1, const float* __restrict__ Wc1,
    const float* __restrict__ Wrel, const float* __restrict__ Wc2,
    unsigned short* __restrict__ Wm1p, unsigned short* __restrict__ Wm2p,
    unsigned short* __restrict__ Wn1p, unsigned short* __restrict__ Wn2p,
    unsigned short* __restrict__ We1p, unsigned short* __restrict__ Wc1p,
    unsigned short* __restrict__ Wrelp, unsigned short* __restrict__ Wc2p)
{
    const int b = blockIdx.x;
    if (b < 144)        pack_block(Wm1, Wm1p, 273, 0, b);
    else if (b < 208)   pack_block(Wm2, Wm2p, 128, 0, b - 144);
    else if (b < 336)   pack_block(Wn1, Wn1p, 256, 0, b - 208);
    else if (b < 400)   pack_block(Wn2, Wn2p, 128, 0, b - 336);
    else if (b < 544)   pack_block(We1, We1p, 257, 1, b - 400);
    else if (b < 1056) {
        const int bb = b - 544, batch = bb >> 6;
        pack_block(Wc1 + (size_t)batch * 16384, Wc1p + (size_t)batch * 16384, 128, 0, bb & 63);
    } else if (b < 1568) {
        const int bb = b - 1056, batch = bb >> 6;
        pack_block(Wrel + (size_t)batch * 16384, Wrelp + (size_t)batch * 16384, 128, 0, bb & 63);
    } else {
        const int bb = b - 1568, r = bb >> 3;
        const int p = (bb & 7) * 256 + threadIdx.x;
        const int j = p & 7, n16 = (p >> 3) & 15, q = (p >> 7) & 3, c = (p >> 9) & 3;
        const int k = c * 32 + q * 8 + j;
        float v = (n16 < 4) ? Wc2[(size_t)r * 512 + k * 4 + n16] * 256.0f : 0.f;
        Wc2p[(size_t)r * 2048 + p] = f2h(v);
    }
}

// ============ radial norm-squared accumulation ============
__global__ __launch_bounds__(256) void k_norm(const float* __restrict__ coord,
                                              const int* __restrict__ edges,
                                              float* __restrict__ nsq)
{
    const int r = blockIdx.x;
    const int tid = threadIdx.x;
    const int* rows = edges + r * 2 * EE;
    const int* cols = rows + EE;
    float acc[16];
#pragma unroll
    for (int i = 0; i < 16; i++) acc[i] = 0.f;
    const int e0 = blockIdx.y * 1024;
    for (int e = e0 + tid; e < e0 + 1024; e += 256) {
        const float4* cr = (const float4*)(coord + (size_t)rows[e] * 12);
        const float4* cc = (const float4*)(coord + (size_t)cols[e] * 12);
        float4 a0 = cr[0], a1 = cr[1], a2 = cr[2];
        float4 b0 = cc[0], b1 = cc[1], b2 = cc[2];
        float cd[12] = { a0.x-b0.x, a0.y-b0.y, a0.z-b0.z, a0.w-b0.w,
                         a1.x-b1.x, a1.y-b1.y, a1.z-b1.z, a1.w-b1.w,
                         a2.x-b2.x, a2.y-b2.y, a2.z-b2.z, a2.w-b2.w };
#pragma unroll
        for (int c = 0; c < 4; c++)
#pragma unroll
            for (int d = 0; d < 4; d++) {
                float v = cd[c*3]*cd[d*3] + cd[c*3+1]*cd[d*3+1] + cd[c*3+2]*cd[d*3+2];
                acc[c*4+d] += v * v;
            }
    }
#pragma unroll
    for (int i = 0; i < 16; i++) {
        float v = acc[i];
        for (int off = 32; off; off >>= 1) v += __shfl_down(v, off, 64);
        if ((tid & 63) == 0) atomicAdd(&nsq[r * 16 + i], v);
    }
}

// ============ message MLP + phi + scatters (128 edges, 512 threads) ============
__global__ __launch_bounds__(512, 6) void k_msg(
    const unsigned short* __restrict__ h_bf, const float* __restrict__ coord,
    const float* __restrict__ eattr, const int* __restrict__ edges,
    const float* __restrict__ nsq,
    const unsigned short* __restrict__ Wm1p, const float* __restrict__ bm1,
    const unsigned short* __restrict__ Wm2p, const float* __restrict__ bm2,
    const unsigned short* __restrict__ Wc1p, const float* __restrict__ bc1,
    const unsigned short* __restrict__ Wc2p,
    float* __restrict__ sAccum, float* __restrict__ cnt,
    unsigned short* __restrict__ seg)
{
    __shared__ __align__(16) unsigned short shT[128 * 136]; // t1 -> ef -> hid
    __shared__ __align__(16) unsigned short shX[128 * 40];  // radial|eattr chunk
    __shared__ float shPhi[128 * 4];
    __shared__ int shRow[128], shCol[128];
    __shared__ float shInv[16];

    const int tid = threadIdx.x;
    const int lane = tid & 63, wid = tid >> 6;
    const int n16 = lane & 15, q = lane >> 4;
    const int ko = q * 8;
    const int r = blockIdx.y;
    const int e0 = blockIdx.x * 128;

    if (tid < 128) shRow[tid] = edges[r * 2 * EE + e0 + tid];
    else if (tid < 256) shCol[tid - 128] = edges[r * 2 * EE + EE + e0 + (tid - 128)];
    else if (tid < 272) {
        const float nv = nsq[r * 16 + (tid - 256)];
        shInv[tid - 256] = 1.0f / fmaxf(sqrtf(nv), 1e-12f);
    }
    __syncthreads();

    if (tid < 128) {
        const int e = tid;
        const float4* cr = (const float4*)(coord + (size_t)shRow[e] * 12);
        const float4* cc = (const float4*)(coord + (size_t)shCol[e] * 12);
        float4 a0 = cr[0], a1 = cr[1], a2 = cr[2];
        float4 b0 = cc[0], b1 = cc[1], b2 = cc[2];
        float cd[12] = { a0.x-b0.x, a0.y-b0.y, a0.z-b0.z, a0.w-b0.w,
                         a1.x-b1.x, a1.y-b1.y, a1.z-b1.z, a1.w-b1.w,
                         a2.x-b2.x, a2.y-b2.y, a2.z-b2.z, a2.w-b2.w };
#pragma unroll
        for (int c = 0; c < 4; c++)
#pragma unroll
            for (int d = 0; d < 4; d++) {
                float v = cd[c*3]*cd[d*3] + cd[c*3+1]*cd[d*3+1] + cd[c*3+2]*cd[d*3+2];
                shX[e * 40 + c * 4 + d] = f2h(v * shInv[c * 4 + d]);
            }
        shX[e * 40 + 16] = f2h(eattr[(size_t)r * EE + e0 + e]);
#pragma unroll
        for (int k2 = 17; k2 < 32; k2++) shX[e * 40 + k2] = 0;
    }
    int rowN[8], colN[8];
#pragma unroll
    for (int m = 0; m < 8; m++) {
        rowN[m] = shRow[m * 16 + n16];
        colN[m] = shCol[m * 16 + n16];
    }
    __syncthreads();

    f32x4 acc[8];
    zero8(acc);
#pragma unroll
    for (int c = 0; c < 4; c++) gchunk8(Wm1p, c,     h_bf, rowN, c * 32, wid, q, n16, acc);
#pragma unroll
    for (int c = 0; c < 4; c++) gchunk8(Wm1p, c + 4, h_bf, colN, c * 32, wid, q, n16, acc);
    {   // chunk 8: radial|eattr from shX
        half8 b = *(const half8*)(Wm1p + (size_t)((8 * 8 + wid) * 4 + q) * 128 + n16 * 8);
#pragma unroll
        for (int m = 0; m < 8; m++) {
            half8 a = *(const half8*)(shX + (m * 16 + n16) * 40 + ko);
            acc[m] = MFMA16(a, b, acc[m]);
        }
    }
    store_act8(acc, bm1, shT, n16, q, wid, true);        // t1
    __syncthreads();

    zero8(acc);
    gemm_lds8<4>(Wm2p, shT, wid, q, n16, acc);           // t1 @ Wm2
    __syncthreads();                                     // all done reading t1
    store_act8(acc, bm2, shT, n16, q, wid, true);        // ef (overwrite)
    __syncthreads();

    zero8(acc);
    gemm_lds8<4>(Wc1p + (size_t)r * 16384, shT, wid, q, n16, acc);   // ef @ Wc1
    {   // seg += ef, packed f16 atomics straight from the ef tile
        unsigned short* segr = seg + (size_t)r * NN * 128;
        for (int it = tid; it < 128 * 64; it += 512) {
            const int e = it >> 6, jj = it & 63;
            const unsigned bits = *(const unsigned*)(shT + e * 136 + jj * 2);
            seg_atomic(segr + (size_t)shRow[e] * 128 + jj * 2, bits);
        }
    }
    __syncthreads();                                     // done reading ef
    store_act8(acc, bc1 + r * 128, shT, n16, q, wid, true);  // hid
    __syncthreads();

    // phi = hid @ Wc2p[r] / 256; wave w handles m-tile w (rows w*16..)
    {
        f32x4 ap = (f32x4)0.f;
        const unsigned short* Bw = Wc2p + (size_t)r * 2048;
#pragma unroll
        for (int c = 0; c < 4; c++) {
            half8 a = *(const half8*)(shT + (wid * 16 + n16) * 136 + c * 32 + ko);
            half8 b = *(const half8*)(Bw + (c * 4 + q) * 128 + n16 * 8);
            ap = MFMA16(a, b, ap);
        }
        if (n16 < 4) {
#pragma unroll
            for (int rr = 0; rr < 4; rr++)
                shPhi[(wid * 16 + q * 4 + rr) * 4 + n16] = ap[rr] * (1.0f / 256.0f);
        }
    }
    __syncthreads();

    if (tid < 128) {
        const int e = tid;
        const int ro = shRow[e];
        const float4* cr = (const float4*)(coord + (size_t)ro * 12);
        const float4* cc = (const float4*)(coord + (size_t)shCol[e] * 12);
        float4 a0 = cr[0], a1 = cr[1], a2 = cr[2];
        float4 b0 = cc[0], b1 = cc[1], b2 = cc[2];
        float cd[12] = { a0.x-b0.x, a0.y-b0.y, a0.z-b0.z, a0.w-b0.w,
                         a1.x-b1.x, a1.y-b1.y, a1.z-b1.z, a1.w-b1.w,
                         a2.x-b2.x, a2.y-b2.y, a2.z-b2.z, a2.w-b2.w };
        float ph[4] = { shPhi[e*4], shPhi[e*4+1], shPhi[e*4+2], shPhi[e*4+3] };
#pragma unroll
        for (int c = 0; c < 4; c++)
#pragma unroll
            for (int d = 0; d < 3; d++)
                atomicAdd(&sAccum[(size_t)ro * 12 + c * 3 + d], cd[c*3+d] * ph[c]);
        atomicAdd(&cnt[ro], 1.0f);
    }
}

// ============ node: agg GEMM (seg@Wrel) + node MLP + coord (64 nodes/block) ============
__device__ __forceinline__ void mfma_chunk4(const unsigned short* __restrict__ Bp, int c,
                                            int wid, int q, int n16,
                                            const half8 a[4], f32x4 acc[4][2])
{
    const unsigned short* bb = Bp + (size_t)(((c * 8 + 2 * wid) * 4) + q) * 128 + n16 * 8;
    half8 b0 = *(const half8*)bb;
    half8 b1 = *(const half8*)(bb + 512);
#pragma unroll
    for (int m = 0; m < 4; m++) {
        acc[m][0] = MFMA16(a[m], b0, acc[m][0]);
        acc[m][1] = MFMA16(a[m], b1, acc[m][1]);
    }
}

__global__ __launch_bounds__(256, 2) void k_node(
    const float* __restrict__ h, const unsigned short* __restrict__ h_bf,
    const float* __restrict__ coord,
    const unsigned short* __restrict__ seg, const float* __restrict__ sAccum,
    const float* __restrict__ cnt,
    const unsigned short* __restrict__ Wrelp,
    const unsigned short* __restrict__ Wn1p, const float* __restrict__ bn1,
    const unsigned short* __restrict__ Wn2p, const float* __restrict__ bn2,
    float* __restrict__ out, unsigned short* __restrict__ hnew_bf)
{
    __shared__ __align__(16) unsigned short shAgg[64 * 136];
    __shared__ __align__(16) unsigned short shT[64 * 136];
    const int tid = threadIdx.x;
    const int lane = tid & 63, wid = tid >> 6;
    const int n16 = lane & 15, q = lane >> 4;
    const int n0 = blockIdx.x * 64;
    const int ko = q * 8;

    int nodeA[4];
#pragma unroll
    for (int m = 0; m < 4; m++) nodeA[m] = min(n0 + m * 16 + n16, NN - 1);

    f32x4 acc[4][2];
#pragma unroll
    for (int m = 0; m < 4; m++) { acc[m][0] = (f32x4)0.f; acc[m][1] = (f32x4)0.f; }
#pragma unroll
    for (int r = 0; r < RR; r++) {
        const unsigned short* segr = seg + (size_t)r * NN * 128;
        const unsigned short* Bp = Wrelp + (size_t)r * 16384;
#pragma unroll
        for (int c = 0; c < 4; c++) {
            half8 a[4];
#pragma unroll
            for (int m = 0; m < 4; m++)
                a[m] = *(const half8*)(segr + (size_t)nodeA[m] * 128 + c * 32 + ko);
            mfma_chunk4(Bp, c, wid, q, n16, a, acc);
        }
    }
    // agg -> shAgg
#pragma unroll
    for (int i = 0; i < 2; i++) {
        const int n = (2 * wid + i) * 16 + n16;
#pragma unroll
        for (int m = 0; m < 4; m++)
#pragma unroll
            for (int rr = 0; rr < 4; rr++)
                shAgg[(m * 16 + q * 4 + rr) * 136 + n] = f2h(acc[m][i][rr]);
    }
    __syncthreads();

#pragma unroll
    for (int m = 0; m < 4; m++) { acc[m][0] = (f32x4)0.f; acc[m][1] = (f32x4)0.f; }
#pragma unroll
    for (int c = 0; c < 4; c++) {
        half8 a[4];
#pragma unroll
        for (int m = 0; m < 4; m++)
            a[m] = *(const half8*)(h_bf + (size_t)nodeA[m] * 128 + c * 32 + ko);
        mfma_chunk4(Wn1p, c, wid, q, n16, a, acc);
    }
#pragma unroll
    for (int c = 4; c < 8; c++) {
        half8 a[4];
#pragma unroll
        for (int m = 0; m < 4; m++)
            a[m] = *(const half8*)(shAgg + (m * 16 + n16) * 136 + (c - 4) * 32 + ko);
        mfma_chunk4(Wn1p, c, wid, q, n16, a, acc);
    }
    // silu -> shT
#pragma unroll
    for (int i = 0; i < 2; i++) {
        const int n = (2 * wid + i) * 16 + n16;
        const float bb = bn1[n];
#pragma unroll
        for (int m = 0; m < 4; m++)
#pragma unroll
            for (int rr = 0; rr < 4; rr++)
                shT[(m * 16 + q * 4 + rr) * 136 + n] = f2h(silu_f(acc[m][i][rr] + bb));
    }
    __syncthreads();

#pragma unroll
    for (int m = 0; m < 4; m++) { acc[m][0] = (f32x4)0.f; acc[m][1] = (f32x4)0.f; }
#pragma unroll
    for (int c = 0; c < 4; c++) {
        half8 a[4];
#pragma unroll
        for (int m = 0; m < 4; m++)
            a[m] = *(const half8*)(shT + (m * 16 + n16) * 136 + c * 32 + ko);
        mfma_chunk4(Wn2p, c, wid, q, n16, a, acc);
    }
#pragma unroll
    for (int i = 0; i < 2; i++) {
        const int n = (2 * wid + i) * 16 + n16;
        const float bb = bn2[n];
#pragma unroll
        for (int m = 0; m < 4; m++)
#pragma unroll
            for (int rr = 0; rr < 4; rr++) {
                const int node = n0 + m * 16 + q * 4 + rr;
                if (node < NN) {
                    const float v = h[(size_t)node * 128 + n] + acc[m][i][rr] + bb;
                    out[(size_t)node * 128 + n] = v;
                    hnew_bf[(size_t)node * 128 + n] = f2h(v);
                }
            }
    }
    if (tid < 64) {
        const int node = n0 + tid;
        if (node < NN) {
            const float ic = 1.0f / fmaxf(cnt[node], 1.0f);
#pragma unroll
            for (int j2 = 0; j2 < 12; j2++)
                out[OUT_X + (size_t)node * 12 + j2] =
                    coord[(size_t)node * 12 + j2] + sAccum[(size_t)node * 12 + j2] * ic;
        }
    }
}

// ============ edge output m (128 edges, 512 threads) ============
__global__ __launch_bounds__(512, 6) void k_edge(
    const unsigned short* __restrict__ hnew_bf, const float* __restrict__ eattr,
    const int* __restrict__ edges,
    const unsigned short* __restrict__ We1p, const float* __restrict__ be1,
    const float* __restrict__ We2, const float* __restrict__ be2,
    float* __restrict__ mout)
{
    __shared__ __align__(16) unsigned short shT[128 * 136];
    __shared__ __align__(16) unsigned short shX[128 * 40];
    __shared__ int shRow[128], shCol[128];
    __shared__ float shW[128];
    const int tid = threadIdx.x;
    const int lane = tid & 63, wid = tid >> 6;
    const int n16 = lane & 15, q = lane >> 4;
    const int ko = q * 8;
    const int r = blockIdx.y;
    const int e0 = blockIdx.x * 128;

    if (tid < 128) shRow[tid] = edges[r * 2 * EE + e0 + tid];
    else if (tid < 256) shCol[tid - 128] = edges[r * 2 * EE + EE + e0 + (tid - 128)];
    else if (tid < 384) shW[tid - 256] = We2[tid - 256];
    __syncthreads();

    if (tid < 128) {
        shX[tid * 40] = f2h(eattr[(size_t)r * EE + e0 + tid]);
#pragma unroll
        for (int k2 = 1; k2 < 32; k2++) shX[tid * 40 + k2] = 0;
    }
    int rowN[8], colN[8];
#pragma unroll
    for (int m = 0; m < 8; m++) {
        rowN[m] = shRow[m * 16 + n16];
        colN[m] = shCol[m * 16 + n16];
    }
    __syncthreads();

    f32x4 acc[8];
    zero8(acc);
#pragma unroll
    for (int c = 0; c < 4; c++) gchunk8(We1p, c,     hnew_bf, rowN, c * 32, wid, q, n16, acc);
#pragma unroll
    for (int c = 0; c < 4; c++) gchunk8(We1p, c + 4, hnew_bf, colN, c * 32, wid, q, n16, acc);
    {
        half8 b = *(const half8*)(We1p + (size_t)((8 * 8 + wid) * 4 + q) * 128 + n16 * 8);
#pragma unroll
        for (int m = 0; m < 8; m++) {
            half8 a = *(const half8*)(shX + (m * 16 + n16) * 40 + ko);
            acc[m] = MFMA16(a, b, acc[m]);
        }
    }
    store_act8(acc, be1, shT, n16, q, wid, true);
    __syncthreads();

    const int e = tid >> 2, qq = tid & 3;
    const unsigned short* trow = shT + e * 136 + qq * 32;
    float p = 0.f;
#pragma unroll
    for (int k = 0; k < 32; k++) p = fmaf(h2f(trow[k]), shW[qq * 32 + k], p);
    p += __shfl_down(p, 2, 4);
    p += __shfl_down(p, 1, 4);
    if (qq == 0) mout[(size_t)r * EE + e0 + e] = p + be2[0];
}

extern "C" void kernel_launch(void* const* d_in, const int* in_sizes, int n_in,
                              void* d_out, int out_size, void* d_ws, size_t ws_size,
                              hipStream_t stream)
{
    const float* h     = (const float*)d_in[0];
    const float* coord = (const float*)d_in[1];
    const float* eattr = (const float*)d_in[2];
    const int*   edges = (const int*)d_in[3];
    const float* Wm1 = (const float*)d_in[4];
    const float* bm1 = (const float*)d_in[5];
    const float* Wm2 = (const float*)d_in[6];
    const float* bm2 = (const float*)d_in[7];
    const float* We1 = (const float*)d_in[8];
    const float* be1 = (const float*)d_in[9];
    const float* We2 = (const float*)d_in[10];
    const float* be2 = (const float*)d_in[11];
    const float* Wn1 = (const float*)d_in[12];
    const float* bn1 = (const float*)d_in[13];
    const float* Wn2 = (const float*)d_in[14];
    const float* bn2 = (const float*)d_in[15];
    const float* Wrel = (const float*)d_in[16];
    const float* Wc1 = (const float*)d_in[17];
    const float* bc1 = (const float*)d_in[18];
    const float* Wc2 = (const float*)d_in[19];

    float* out = (float*)d_out;
    float* ws  = (float*)d_ws;

    float* nsq      = ws;            // 128 (16 used/relation)
    float* cnt      = ws + 256;      // 20000
    float* sAccum   = ws + 20256;    // 240000 -> zero region ends at 260256 f32
    unsigned short* U = (unsigned short*)(ws + 260256);
    unsigned short* seg     = U;                   // 8*20000*128 = 20,480,000 (zeroed)
    unsigned short* h_bf    = U + 20480000;        // 2,560,000
    unsigned short* hnew_bf = U + 23040000;        // 2,560,000
    unsigned short* Wm1p    = U + 25600000;        // 36,864
    unsigned short* Wm2p    = U + 25636864;        // 16,384
    unsigned short* Wn1p    = U + 25653248;        // 32,768
    unsigned short* Wn2p    = U + 25686016;        // 16,384
    unsigned short* We1p    = U + 25702400;        // 36,864
    unsigned short* Wc1p    = U + 25739264;        // 131,072
    unsigned short* Wrelp   = U + 25870336;        // 131,072
    unsigned short* Wc2p    = U + 26001408;        // 16,384

    hipMemsetAsync(d_ws, 0, (size_t)260256 * 4 + (size_t)20480000 * 2, stream);

    k_cvt_h<<<2500, 256, 0, stream>>>(h, h_bf);
    k_pack_all<<<1632, 256, 0, stream>>>(Wm1, Wm2, Wn1, Wn2, We1, Wc1, Wrel, Wc2,
        Wm1p, Wm2p, Wn1p, Wn2p, We1p, Wc1p, Wrelp, Wc2p);
    k_norm<<<dim3(RR, 32), 256, 0, stream>>>(coord, edges, nsq);
    k_msg<<<dim3(EE / 128, RR), 512, 0, stream>>>(h_bf, coord, eattr, edges, nsq,
        Wm1p, bm1, Wm2p, bm2, Wc1p, bc1, Wc2p, sAccum, cnt, seg);
    k_node<<<(NN + 63) / 64, 256, 0, stream>>>(h, h_bf, coord, seg, sAccum, cnt,
        Wrelp, Wn1p, bn1, Wn2p, bn2, out, hnew_bf);
    k_edge<<<dim3(EE / 128, RR), 512, 0, stream>>>(hnew_bf, eattr, edges,
        We1p, be1, We2, be2, out + OUT_M);
}

// Round 5
// 489.706 us; speedup vs baseline: 1.4053x; 1.4053x over previous
//
#include <hip/hip_runtime.h>
#include <hip/hip_fp16.h>
#include <cmath>

#define NN 20000
#define FF 128
#define EE 32768
#define RR 8

#define OUT_X (NN*FF)            // 2,560,000
#define OUT_M (NN*FF + NN*12)    // 2,800,000

typedef _Float16 half8 __attribute__((ext_vector_type(8)));
typedef float f32x4 __attribute__((ext_vector_type(4)));

#define MFMA16(a,b,c) __builtin_amdgcn_mfma_f32_16x16x32_f16(a, b, c, 0, 0, 0)
#define SCHED_FENCE() asm volatile("" ::: "memory")

__device__ __forceinline__ float silu_f(float x) {
    return x / (1.0f + __expf(-x));
}
__device__ __forceinline__ unsigned short f2h(float x) {
    _Float16 h = (_Float16)x;
    return __builtin_bit_cast(unsigned short, h);
}
__device__ __forceinline__ float h2f(unsigned short u) {
    return (float)__builtin_bit_cast(_Float16, u);
}

__device__ __forceinline__ void seg_atomic(unsigned short* p, unsigned bits) {
#if __has_builtin(__builtin_amdgcn_flat_atomic_fadd_v2f16)
    typedef _Float16 v2h __attribute__((ext_vector_type(2)));
    v2h v = __builtin_bit_cast(v2h, bits);
    __builtin_amdgcn_flat_atomic_fadd_v2f16((v2h*)p, v);
#else
    __half2 v = __builtin_bit_cast(__half2, bits);
    unsafeAtomicAdd((__half2*)p, v);
#endif
}

// ---- row-split GEMM helpers: wave owns 2 m-tiles (32 edges) x 8 n-tiles ----
__device__ __forceinline__ void zz(f32x4 A0[8], f32x4 A1[8]) {
#pragma unroll
    for (int t = 0; t < 8; t++) { A0[t] = (f32x4)0.f; A1[t] = (f32x4)0.f; }
}

__device__ __forceinline__ void mm_chunk(const unsigned short* __restrict__ Bp, int c,
                                         half8 a0, half8 a1, int q, int n16,
                                         f32x4 A0[8], f32x4 A1[8])
{
#pragma unroll
    for (int t = 0; t < 8; t++) {
        half8 b = *(const half8*)(Bp + (size_t)((c * 8 + t) * 4 + q) * 128 + n16 * 8);
        A0[t] = MFMA16(a0, b, A0[t]);
        A1[t] = MFMA16(a1, b, A1[t]);
    }
}

// A from wave-private LDS scratch (32 x 136)
template<int NCH>
__device__ __forceinline__ void gemm_sw(const unsigned short* __restrict__ Bp,
                                        const unsigned short* sW, int q, int n16,
                                        f32x4 A0[8], f32x4 A1[8])
{
#pragma unroll
    for (int c = 0; c < NCH; c++) {
        half8 a0 = *(const half8*)(sW + n16 * 136 + c * 32 + q * 8);
        half8 a1 = *(const half8*)(sW + (16 + n16) * 136 + c * 32 + q * 8);
        mm_chunk(Bp, c, a0, a1, q, n16, A0, A1);
    }
}

// C/D layout: col = lane&15, row = (lane>>4)*4 + reg
__device__ __forceinline__ void store2(f32x4 A0[8], f32x4 A1[8], const float* __restrict__ bias,
                                       unsigned short* sW, int n16, int q, bool dosilu)
{
#pragma unroll
    for (int t = 0; t < 8; t++) {
        const float bb = bias[t * 16 + n16];
#pragma unroll
        for (int rr = 0; rr < 4; rr++) {
            float v0 = A0[t][rr] + bb, v1 = A1[t][rr] + bb;
            if (dosilu) { v0 = silu_f(v0); v1 = silu_f(v1); }
            sW[(q * 4 + rr) * 136 + t * 16 + n16] = f2h(v0);
            sW[(16 + q * 4 + rr) * 136 + t * 16 + n16] = f2h(v1);
        }
    }
}

// ============ prep: h -> f16 ============
__global__ __launch_bounds__(256) void k_cvt_h(const float* __restrict__ h,
                                               unsigned short* __restrict__ h_bf)
{
    const int i = (blockIdx.x * 256 + threadIdx.x) * 4;
    float4 v = *(const float4*)(h + i);
    unsigned short u[4] = { f2h(v.x), f2h(v.y), f2h(v.z), f2h(v.w) };
    *(uint2*)(h_bf + i) = *(const uint2*)u;
}

// ============ fused weight pack ============
__device__ __forceinline__ void pack_block(const float* __restrict__ Wb,
                                           unsigned short* __restrict__ db,
                                           int K, int remap, int blk)
{
    const int p = blk * 256 + threadIdx.x;
    const int j = p & 7, n16 = (p >> 3) & 15, q = (p >> 7) & 3, t = (p >> 9) & 7, c = p >> 12;
    int k = c * 32 + q * 8 + j;
    if (remap) k = (k < 128) ? k : (k < 256) ? (k + 1) : (k == 256 ? 128 : K);
    const int n = t * 16 + n16;
    db[p] = f2h((k < K) ? Wb[(size_t)k * 128 + n] : 0.f);
}

__global__ __launch_bounds__(256) void k_pack_all(
    const float* __restrict__ Wm1, const float* __restrict__ Wm2,
    const float* __restrict__ Wn1, const float* __restrict__ Wn2,
    const float* __restrict__ We1, const float* __restrict__ Wc1,
    const float* __restrict__ Wrel, const float* __restrict__ Wc2,
    unsigned short* __restrict__ Wm1p, unsigned short* __restrict__ Wm2p,
    unsigned short* __restrict__ Wn1p, unsigned short* __restrict__ Wn2p,
    unsigned short* __restrict__ We1p, unsigned short* __restrict__ Wc1p,
    unsigned short* __restrict__ Wrelp, unsigned short* __restrict__ Wc2p)
{
    const int b = blockIdx.x;
    if (b < 144)        pack_block(Wm1, Wm1p, 273, 0, b);
    else if (b < 208)   pack_block(Wm2, Wm2p, 128, 0, b - 144);
    else if (b < 336)   pack_block(Wn1, Wn1p, 256, 0, b - 208);
    else if (b < 400)   pack_block(Wn2, Wn2p, 128, 0, b - 336);
    else if (b < 544)   pack_block(We1, We1p, 257, 1, b - 400);
    else if (b < 1056) {
        const int bb = b - 544, batch = bb >> 6;
        pack_block(Wc1 + (size_t)batch * 16384, Wc1p + (size_t)batch * 16384, 128, 0, bb & 63);
    } else if (b < 1568) {
        const int bb = b - 1056, batch = bb >> 6;
        pack_block(Wrel + (size_t)batch * 16384, Wrelp + (size_t)batch * 16384, 128, 0, bb & 63);
    } else {
        const int bb = b - 1568, r = bb >> 3;
        const int p = (bb & 7) * 256 + threadIdx.x;
        const int j = p & 7, n16 = (p >> 3) & 15, q = (p >> 7) & 3, c = (p >> 9) & 3;
        const int k = c * 32 + q * 8 + j;
        float v = (n16 < 4) ? Wc2[(size_t)r * 512 + k * 4 + n16] * 256.0f : 0.f;
        Wc2p[(size_t)r * 2048 + p] = f2h(v);
    }
}

// ============ radial norm-squared accumulation ============
__global__ __launch_bounds__(256) void k_norm(const float* __restrict__ coord,
                                              const int* __restrict__ edges,
                                              float* __restrict__ nsq)
{
    const int r = blockIdx.x;
    const int tid = threadIdx.x;
    const int* rows = edges + r * 2 * EE;
    const int* cols = rows + EE;
    float acc[16];
#pragma unroll
    for (int i = 0; i < 16; i++) acc[i] = 0.f;
    const int e0 = blockIdx.y * 1024;
    for (int e = e0 + tid; e < e0 + 1024; e += 256) {
        const float4* cr = (const float4*)(coord + (size_t)rows[e] * 12);
        const float4* cc = (const float4*)(coord + (size_t)cols[e] * 12);
        float4 a0 = cr[0], a1 = cr[1], a2 = cr[2];
        float4 b0 = cc[0], b1 = cc[1], b2 = cc[2];
        float cd[12] = { a0.x-b0.x, a0.y-b0.y, a0.z-b0.z, a0.w-b0.w,
                         a1.x-b1.x, a1.y-b1.y, a1.z-b1.z, a1.w-b1.w,
                         a2.x-b2.x, a2.y-b2.y, a2.z-b2.z, a2.w-b2.w };
#pragma unroll
        for (int c = 0; c < 4; c++)
#pragma unroll
            for (int d = 0; d < 4; d++) {
                float v = cd[c*3]*cd[d*3] + cd[c*3+1]*cd[d*3+1] + cd[c*3+2]*cd[d*3+2];
                acc[c*4+d] += v * v;
            }
    }
#pragma unroll
    for (int i = 0; i < 16; i++) {
        float v = acc[i];
        for (int off = 32; off; off >>= 1) v += __shfl_down(v, off, 64);
        if ((tid & 63) == 0) atomicAdd(&nsq[r * 16 + i], v);
    }
}

// ============ message MLP + phi + scatters ============
// 256 threads, 4 waves; wave owns 32 edges; barrier-free (wave-private LDS)
__global__ __launch_bounds__(256, 4) void k_msg(
    const unsigned short* __restrict__ h_bf, const float* __restrict__ coord,
    const float* __restrict__ eattr, const int* __restrict__ edges,
    const float* __restrict__ nsq,
    const unsigned short* __restrict__ Wm1p, const float* __restrict__ bm1,
    const unsigned short* __restrict__ Wm2p, const float* __restrict__ bm2,
    const unsigned short* __restrict__ Wc1p, const float* __restrict__ bc1,
    const unsigned short* __restrict__ Wc2p,
    float* __restrict__ sAccum, float* __restrict__ cnt,
    unsigned short* __restrict__ seg)
{
    __shared__ __align__(16) unsigned short shW[4][32 * 136];
    __shared__ float shPhi[4][32 * 4];

    const int tid = threadIdx.x;
    const int wid = tid >> 6, lane = tid & 63;
    const int n16 = lane & 15, q = lane >> 4;
    const int r = blockIdx.y;
    const int e0 = blockIdx.x * 128 + wid * 32;

    unsigned short* sW = shW[wid];
    float* sPhi = shPhi[wid];

    const int eA0 = e0 + n16, eA1 = e0 + 16 + n16;
    int rowN[2], colN[2];
    rowN[0] = edges[r * 2 * EE + eA0];
    rowN[1] = edges[r * 2 * EE + eA1];
    colN[0] = edges[r * 2 * EE + EE + eA0];
    colN[1] = edges[r * 2 * EE + EE + eA1];

    // ---- chunk-8 A fragments (radial|eattr|pad) in registers ----
    half8 aX0 = (half8)(_Float16)0.0f, aX1 = (half8)(_Float16)0.0f;
    if (q < 2) {
        const float4 i4a = *(const float4*)(nsq + r * 16 + q * 8);
        const float4 i4b = *(const float4*)(nsq + r * 16 + q * 8 + 4);
        float nv[8] = { i4a.x, i4a.y, i4a.z, i4a.w, i4b.x, i4b.y, i4b.z, i4b.w };
        float inv[8];
#pragma unroll
        for (int j = 0; j < 8; j++) inv[j] = 1.0f / fmaxf(sqrtf(nv[j]), 1e-12f);
#pragma unroll
        for (int m = 0; m < 2; m++) {
            const float* cr = coord + (size_t)rowN[m] * 12;
            const float* cc = coord + (size_t)colN[m] * 12;
            float cd[12];
#pragma unroll
            for (int i2 = 0; i2 < 12; i2++) cd[i2] = cr[i2] - cc[i2];
            half8 t = (half8)(_Float16)0.0f;
#pragma unroll
            for (int j = 0; j < 8; j++) {
                const int kk = q * 8 + j, c = kk >> 2, d = kk & 3;
                float v = cd[c*3]*cd[d*3] + cd[c*3+1]*cd[d*3+1] + cd[c*3+2]*cd[d*3+2];
                t[j] = (_Float16)(v * inv[j]);
            }
            if (m == 0) aX0 = t; else aX1 = t;
        }
    } else if (q == 2) {
        aX0[0] = (_Float16)eattr[(size_t)r * EE + eA0];
        aX1[0] = (_Float16)eattr[(size_t)r * EE + eA1];
    }

    // ---- layer 1: msg @ Wm1 ----
    f32x4 A0[8], A1[8];
    zz(A0, A1);
#pragma unroll
    for (int c = 0; c < 4; c++) {
        half8 a0 = *(const half8*)(h_bf + (size_t)rowN[0] * 128 + c * 32 + q * 8);
        half8 a1 = *(const half8*)(h_bf + (size_t)rowN[1] * 128 + c * 32 + q * 8);
        mm_chunk(Wm1p, c, a0, a1, q, n16, A0, A1);
    }
#pragma unroll
    for (int c = 0; c < 4; c++) {
        half8 a0 = *(const half8*)(h_bf + (size_t)colN[0] * 128 + c * 32 + q * 8);
        half8 a1 = *(const half8*)(h_bf + (size_t)colN[1] * 128 + c * 32 + q * 8);
        mm_chunk(Wm1p, c + 4, a0, a1, q, n16, A0, A1);
    }
    mm_chunk(Wm1p, 8, aX0, aX1, q, n16, A0, A1);
    store2(A0, A1, bm1, sW, n16, q, true);            // t1
    SCHED_FENCE();

    // ---- layer 2: t1 @ Wm2 -> ef ----
    zz(A0, A1);
    gemm_sw<4>(Wm2p, sW, q, n16, A0, A1);
    SCHED_FENCE();
    store2(A0, A1, bm2, sW, n16, q, true);            // ef (overwrite)
    SCHED_FENCE();

    // ---- layer 3: ef @ Wc1[r] (+ seg atomics from ef tile) ----
    zz(A0, A1);
    gemm_sw<4>(Wc1p + (size_t)r * 16384, sW, q, n16, A0, A1);
    {
        unsigned short* segr = seg + (size_t)r * NN * 128;
#pragma unroll
        for (int i = 0; i < 32; i++) {
            const int rT = __shfl(rowN[i >> 4], i & 15, 64);
            const unsigned bits = *(const unsigned*)(sW + i * 136 + lane * 2);
            seg_atomic(segr + (size_t)rT * 128 + lane * 2, bits);
        }
    }
    SCHED_FENCE();
    store2(A0, A1, bc1 + r * 128, sW, n16, q, true);  // hid (overwrite)
    SCHED_FENCE();

    // ---- phi = hid @ Wc2p[r] / 256 ----
    {
        f32x4 ap0 = (f32x4)0.f, ap1 = (f32x4)0.f;
        const unsigned short* Bw = Wc2p + (size_t)r * 2048;
#pragma unroll
        for (int c = 0; c < 4; c++) {
            half8 a0 = *(const half8*)(sW + n16 * 136 + c * 32 + q * 8);
            half8 a1 = *(const half8*)(sW + (16 + n16) * 136 + c * 32 + q * 8);
            half8 b = *(const half8*)(Bw + (size_t)(c * 4 + q) * 128 + n16 * 8);
            ap0 = MFMA16(a0, b, ap0);
            ap1 = MFMA16(a1, b, ap1);
        }
        if (n16 < 4) {
#pragma unroll
            for (int rr = 0; rr < 4; rr++) {
                sPhi[(q * 4 + rr) * 4 + n16] = ap0[rr] * (1.0f / 256.0f);
                sPhi[(16 + q * 4 + rr) * 4 + n16] = ap1[rr] * (1.0f / 256.0f);
            }
        }
    }
    SCHED_FENCE();

    // ---- scatter: sAccum += cd * phi ; cnt ----
#pragma unroll
    for (int m = 0; m < 2; m++) {
        const int row = rowN[m], col = colN[m];
        const float ph = sPhi[(m * 16 + n16) * 4 + q];
#pragma unroll
        for (int d = 0; d < 3; d++) {
            const int idx = q * 3 + d;
            const float cdv = coord[(size_t)row * 12 + idx] - coord[(size_t)col * 12 + idx];
            atomicAdd(&sAccum[(size_t)row * 12 + idx], cdv * ph);
        }
        if (q == 0) atomicAdd(&cnt[row], 1.0f);
    }
}

// ============ node: agg GEMM (seg@Wrel) + node MLP + coord ============
__device__ __forceinline__ void mfma_chunk4(const unsigned short* __restrict__ Bp, int c,
                                            int wid, int q, int n16,
                                            const half8 a[4], f32x4 acc[4][2])
{
    const unsigned short* bb = Bp + (size_t)(((c * 8 + 2 * wid) * 4) + q) * 128 + n16 * 8;
    half8 b0 = *(const half8*)bb;
    half8 b1 = *(const half8*)(bb + 512);
#pragma unroll
    for (int m = 0; m < 4; m++) {
        acc[m][0] = MFMA16(a[m], b0, acc[m][0]);
        acc[m][1] = MFMA16(a[m], b1, acc[m][1]);
    }
}

__global__ __launch_bounds__(256, 2) void k_node(
    const float* __restrict__ h, const unsigned short* __restrict__ h_bf,
    const float* __restrict__ coord,
    const unsigned short* __restrict__ seg, const float* __restrict__ sAccum,
    const float* __restrict__ cnt,
    const unsigned short* __restrict__ Wrelp,
    const unsigned short* __restrict__ Wn1p, const float* __restrict__ bn1,
    const unsigned short* __restrict__ Wn2p, const float* __restrict__ bn2,
    float* __restrict__ out, unsigned short* __restrict__ hnew_bf)
{
    __shared__ __align__(16) unsigned short shAgg[64 * 136];
    __shared__ __align__(16) unsigned short shT[64 * 136];
    const int tid = threadIdx.x;
    const int lane = tid & 63, wid = tid >> 6;
    const int n16 = lane & 15, q = lane >> 4;
    const int n0 = blockIdx.x * 64;
    const int ko = q * 8;

    int nodeA[4];
#pragma unroll
    for (int m = 0; m < 4; m++) nodeA[m] = min(n0 + m * 16 + n16, NN - 1);

    f32x4 acc[4][2];
#pragma unroll
    for (int m = 0; m < 4; m++) { acc[m][0] = (f32x4)0.f; acc[m][1] = (f32x4)0.f; }
#pragma unroll
    for (int r = 0; r < RR; r++) {
        const unsigned short* segr = seg + (size_t)r * NN * 128;
        const unsigned short* Bp = Wrelp + (size_t)r * 16384;
#pragma unroll
        for (int c = 0; c < 4; c++) {
            half8 a[4];
#pragma unroll
            for (int m = 0; m < 4; m++)
                a[m] = *(const half8*)(segr + (size_t)nodeA[m] * 128 + c * 32 + ko);
            mfma_chunk4(Bp, c, wid, q, n16, a, acc);
        }
    }
#pragma unroll
    for (int i = 0; i < 2; i++) {
        const int n = (2 * wid + i) * 16 + n16;
#pragma unroll
        for (int m = 0; m < 4; m++)
#pragma unroll
            for (int rr = 0; rr < 4; rr++)
                shAgg[(m * 16 + q * 4 + rr) * 136 + n] = f2h(acc[m][i][rr]);
    }
    __syncthreads();

#pragma unroll
    for (int m = 0; m < 4; m++) { acc[m][0] = (f32x4)0.f; acc[m][1] = (f32x4)0.f; }
#pragma unroll
    for (int c = 0; c < 4; c++) {
        half8 a[4];
#pragma unroll
        for (int m = 0; m < 4; m++)
            a[m] = *(const half8*)(h_bf + (size_t)nodeA[m] * 128 + c * 32 + ko);
        mfma_chunk4(Wn1p, c, wid, q, n16, a, acc);
    }
#pragma unroll
    for (int c = 4; c < 8; c++) {
        half8 a[4];
#pragma unroll
        for (int m = 0; m < 4; m++)
            a[m] = *(const half8*)(shAgg + (m * 16 + n16) * 136 + (c - 4) * 32 + ko);
        mfma_chunk4(Wn1p, c, wid, q, n16, a, acc);
    }
#pragma unroll
    for (int i = 0; i < 2; i++) {
        const int n = (2 * wid + i) * 16 + n16;
        const float bb = bn1[n];
#pragma unroll
        for (int m = 0; m < 4; m++)
#pragma unroll
            for (int rr = 0; rr < 4; rr++)
                shT[(m * 16 + q * 4 + rr) * 136 + n] = f2h(silu_f(acc[m][i][rr] + bb));
    }
    __syncthreads();

#pragma unroll
    for (int m = 0; m < 4; m++) { acc[m][0] = (f32x4)0.f; acc[m][1] = (f32x4)0.f; }
#pragma unroll
    for (int c = 0; c < 4; c++) {
        half8 a[4];
#pragma unroll
        for (int m = 0; m < 4; m++)
            a[m] = *(const half8*)(shT + (m * 16 + n16) * 136 + c * 32 + ko);
        mfma_chunk4(Wn2p, c, wid, q, n16, a, acc);
    }
#pragma unroll
    for (int i = 0; i < 2; i++) {
        const int n = (2 * wid + i) * 16 + n16;
        const float bb = bn2[n];
#pragma unroll
        for (int m = 0; m < 4; m++)
#pragma unroll
            for (int rr = 0; rr < 4; rr++) {
                const int node = n0 + m * 16 + q * 4 + rr;
                if (node < NN) {
                    const float v = h[(size_t)node * 128 + n] + acc[m][i][rr] + bb;
                    out[(size_t)node * 128 + n] = v;
                    hnew_bf[(size_t)node * 128 + n] = f2h(v);
                }
            }
    }
    if (tid < 64) {
        const int node = n0 + tid;
        if (node < NN) {
            const float ic = 1.0f / fmaxf(cnt[node], 1.0f);
#pragma unroll
            for (int j2 = 0; j2 < 12; j2++)
                out[OUT_X + (size_t)node * 12 + j2] =
                    coord[(size_t)node * 12 + j2] + sAccum[(size_t)node * 12 + j2] * ic;
        }
    }
}

// ============ edge output m: row-split, barrier-free ============
__global__ __launch_bounds__(256, 4) void k_edge(
    const unsigned short* __restrict__ hnew_bf, const float* __restrict__ eattr,
    const int* __restrict__ edges,
    const unsigned short* __restrict__ We1p, const float* __restrict__ be1,
    const float* __restrict__ We2, const float* __restrict__ be2,
    float* __restrict__ mout)
{
    __shared__ __align__(16) unsigned short shW[4][32 * 136];
    const int tid = threadIdx.x;
    const int wid = tid >> 6, lane = tid & 63;
    const int n16 = lane & 15, q = lane >> 4;
    const int r = blockIdx.y;
    const int e0 = blockIdx.x * 128 + wid * 32;

    unsigned short* sW = shW[wid];

    const int eA0 = e0 + n16, eA1 = e0 + 16 + n16;
    int rowN[2], colN[2];
    rowN[0] = edges[r * 2 * EE + eA0];
    rowN[1] = edges[r * 2 * EE + eA1];
    colN[0] = edges[r * 2 * EE + EE + eA0];
    colN[1] = edges[r * 2 * EE + EE + eA1];

    half8 aX0 = (half8)(_Float16)0.0f, aX1 = (half8)(_Float16)0.0f;
    if (q == 0) {
        aX0[0] = (_Float16)eattr[(size_t)r * EE + eA0];
        aX1[0] = (_Float16)eattr[(size_t)r * EE + eA1];
    }

    f32x4 A0[8], A1[8];
    zz(A0, A1);
#pragma unroll
    for (int c = 0; c < 4; c++) {
        half8 a0 = *(const half8*)(hnew_bf + (size_t)rowN[0] * 128 + c * 32 + q * 8);
        half8 a1 = *(const half8*)(hnew_bf + (size_t)rowN[1] * 128 + c * 32 + q * 8);
        mm_chunk(We1p, c, a0, a1, q, n16, A0, A1);
    }
#pragma unroll
    for (int c = 0; c < 4; c++) {
        half8 a0 = *(const half8*)(hnew_bf + (size_t)colN[0] * 128 + c * 32 + q * 8);
        half8 a1 = *(const half8*)(hnew_bf + (size_t)colN[1] * 128 + c * 32 + q * 8);
        mm_chunk(We1p, c + 4, a0, a1, q, n16, A0, A1);
    }
    mm_chunk(We1p, 8, aX0, aX1, q, n16, A0, A1);
    store2(A0, A1, be1, sW, n16, q, true);
    SCHED_FENCE();

    // m = silu(t1e) @ We2 + be2 : lane (n16,q) covers k = q*32..q*32+31
    float p0 = 0.f, p1 = 0.f;
#pragma unroll
    for (int kk4 = 0; kk4 < 8; kk4++) {
        const float4 w4 = *(const float4*)(We2 + q * 32 + kk4 * 4);
        const unsigned short* t0 = sW + n16 * 136 + q * 32 + kk4 * 4;
        const unsigned short* t1 = sW + (16 + n16) * 136 + q * 32 + kk4 * 4;
        p0 += h2f(t0[0])*w4.x + h2f(t0[1])*w4.y + h2f(t0[2])*w4.z + h2f(t0[3])*w4.w;
        p1 += h2f(t1[0])*w4.x + h2f(t1[1])*w4.y + h2f(t1[2])*w4.z + h2f(t1[3])*w4.w;
    }
    p0 += __shfl_xor(p0, 16, 64); p0 += __shfl_xor(p0, 32, 64);
    p1 += __shfl_xor(p1, 16, 64); p1 += __shfl_xor(p1, 32, 64);
    if (q == 0) {
        mout[(size_t)r * EE + eA0] = p0 + be2[0];
        mout[(size_t)r * EE + eA1] = p1 + be2[0];
    }
}

extern "C" void kernel_launch(void* const* d_in, const int* in_sizes, int n_in,
                              void* d_out, int out_size, void* d_ws, size_t ws_size,
                              hipStream_t stream)
{
    const float* h     = (const float*)d_in[0];
    const float* coord = (const float*)d_in[1];
    const float* eattr = (const float*)d_in[2];
    const int*   edges = (const int*)d_in[3];
    const float* Wm1 = (const float*)d_in[4];
    const float* bm1 = (const float*)d_in[5];
    const float* Wm2 = (const float*)d_in[6];
    const float* bm2 = (const float*)d_in[7];
    const float* We1 = (const float*)d_in[8];
    const float* be1 = (const float*)d_in[9];
    const float* We2 = (const float*)d_in[10];
    const float* be2 = (const float*)d_in[11];
    const float* Wn1 = (const float*)d_in[12];
    const float* bn1 = (const float*)d_in[13];
    const float* Wn2 = (const float*)d_in[14];
    const float* bn2 = (const float*)d_in[15];
    const float* Wrel = (const float*)d_in[16];
    const float* Wc1 = (const float*)d_in[17];
    const float* bc1 = (const float*)d_in[18];
    const float* Wc2 = (const float*)d_in[19];

    float* out = (float*)d_out;
    float* ws  = (float*)d_ws;

    float* nsq      = ws;            // 128 (16/relation used)
    float* cnt      = ws + 256;      // 20000
    float* sAccum   = ws + 20256;    // 240000 -> zero region ends at 260256 f32
    unsigned short* U = (unsigned short*)(ws + 260256);
    unsigned short* seg     = U;                   // 20,480,000 (zeroed)
    unsigned short* h_bf    = U + 20480000;
    unsigned short* hnew_bf = U + 23040000;
    unsigned short* Wm1p    = U + 25600000;
    unsigned short* Wm2p    = U + 25636864;
    unsigned short* Wn1p    = U + 25653248;
    unsigned short* Wn2p    = U + 25686016;
    unsigned short* We1p    = U + 25702400;
    unsigned short* Wc1p    = U + 25739264;
    unsigned short* Wrelp   = U + 25870336;
    unsigned short* Wc2p    = U + 26001408;

    hipMemsetAsync(d_ws, 0, (size_t)260256 * 4 + (size_t)20480000 * 2, stream);

    k_cvt_h<<<2500, 256, 0, stream>>>(h, h_bf);
    k_pack_all<<<1632, 256, 0, stream>>>(Wm1, Wm2, Wn1, Wn2, We1, Wc1, Wrel, Wc2,
        Wm1p, Wm2p, Wn1p, Wn2p, We1p, Wc1p, Wrelp, Wc2p);
    k_norm<<<dim3(RR, 32), 256, 0, stream>>>(coord, edges, nsq);
    k_msg<<<dim3(EE / 128, RR), 256, 0, stream>>>(h_bf, coord, eattr, edges, nsq,
        Wm1p, bm1, Wm2p, bm2, Wc1p, bc1, Wc2p, sAccum, cnt, seg);
    k_node<<<(NN + 63) / 64, 256, 0, stream>>>(h, h_bf, coord, seg, sAccum, cnt,
        Wrelp, Wn1p, bn1, Wn2p, bn2, out, hnew_bf);
    k_edge<<<dim3(EE / 128, RR), 256, 0, stream>>>(hnew_bf, eattr, edges,
        We1p, be1, We2, be2, out + OUT_M);
}

// Round 7
// 469.306 us; speedup vs baseline: 1.4664x; 1.0435x over previous
//
#include <hip/hip_runtime.h>
#include <hip/hip_fp16.h>
#include <cmath>

#define NN 20000
#define FF 128
#define EE 32768
#define RR 8

#define OUT_X (NN*FF)            // 2,560,000
#define OUT_M (NN*FF + NN*12)    // 2,800,000

typedef _Float16 half8 __attribute__((ext_vector_type(8)));
typedef float f32x4 __attribute__((ext_vector_type(4)));

#define MFMA16(a,b,c) __builtin_amdgcn_mfma_f32_16x16x32_f16(a, b, c, 0, 0, 0)

__device__ __forceinline__ float silu_f(float x) {
    return x / (1.0f + __expf(-x));
}
__device__ __forceinline__ unsigned short f2h(float x) {
    _Float16 h = (_Float16)x;
    return __builtin_bit_cast(unsigned short, h);
}
__device__ __forceinline__ float h2f(unsigned short u) {
    return (float)__builtin_bit_cast(_Float16, u);
}

__device__ __forceinline__ void seg_atomic(unsigned short* p, unsigned bits) {
#if __has_builtin(__builtin_amdgcn_flat_atomic_fadd_v2f16)
    typedef _Float16 v2h __attribute__((ext_vector_type(2)));
    v2h v = __builtin_bit_cast(v2h, bits);
    __builtin_amdgcn_flat_atomic_fadd_v2f16((v2h*)p, v);
#else
    __half2 v = __builtin_bit_cast(__half2, bits);
    unsafeAtomicAdd((__half2*)p, v);
#endif
}

// ---- column-split helpers: wave w covers 4 m-tiles x n-tiles {2w,2w+1} ----
__device__ __forceinline__ void zero42(f32x4 acc[4][2]) {
#pragma unroll
    for (int m = 0; m < 4; m++) { acc[m][0] = (f32x4)0.f; acc[m][1] = (f32x4)0.f; }
}

__device__ __forceinline__ void mfma_chunk4(const unsigned short* __restrict__ Bp, int c,
                                            int wid, int q, int n16,
                                            const half8 a[4], f32x4 acc[4][2])
{
    const unsigned short* bb = Bp + (size_t)(((c * 8 + 2 * wid) * 4) + q) * 128 + n16 * 8;
    half8 b0 = *(const half8*)bb;
    half8 b1 = *(const half8*)(bb + 512);
#pragma unroll
    for (int m = 0; m < 4; m++) {
        acc[m][0] = MFMA16(a[m], b0, acc[m][0]);
        acc[m][1] = MFMA16(a[m], b1, acc[m][1]);
    }
}

// A from LDS tile (64 x NCH*32, stride 136)
template<int NCH>
__device__ __forceinline__ void gemm_lds4(const unsigned short* __restrict__ Bp,
                                          const unsigned short* sA,
                                          int wid, int q, int n16, f32x4 acc[4][2])
{
#pragma unroll
    for (int c = 0; c < NCH; c++) {
        half8 a[4];
#pragma unroll
        for (int m = 0; m < 4; m++)
            a[m] = *(const half8*)(sA + (m * 16 + n16) * 136 + c * 32 + q * 8);
        mfma_chunk4(Bp, c, wid, q, n16, a, acc);
    }
}

// C/D layout: col = lane&15, row = (lane>>4)*4 + reg
__device__ __forceinline__ void store_act4(f32x4 acc[4][2], const float* __restrict__ bias,
                                           unsigned short* sOut, int n16, int q, int wid,
                                           bool dosilu)
{
#pragma unroll
    for (int i = 0; i < 2; i++) {
        const int n = (2 * wid + i) * 16 + n16;
        const float bb = bias[n];
#pragma unroll
        for (int m = 0; m < 4; m++)
#pragma unroll
            for (int rr = 0; rr < 4; rr++) {
                float v = acc[m][i][rr] + bb;
                if (dosilu) v = silu_f(v);
                sOut[(m * 16 + q * 4 + rr) * 136 + n] = f2h(v);
            }
    }
}

// ============ prep: h -> f16 ============
__global__ __launch_bounds__(256) void k_cvt_h(const float* __restrict__ h,
                                               unsigned short* __restrict__ h_bf)
{
    const int i = (blockIdx.x * 256 + threadIdx.x) * 4;
    float4 v = *(const float4*)(h + i);
    unsigned short u[4] = { f2h(v.x), f2h(v.y), f2h(v.z), f2h(v.w) };
    *(uint2*)(h_bf + i) = *(const uint2*)u;
}

// ============ fused weight pack (passed R5) ============
__device__ __forceinline__ void pack_block(const float* __restrict__ Wb,
                                           unsigned short* __restrict__ db,
                                           int K, int remap, int blk)
{
    const int p = blk * 256 + threadIdx.x;
    const int j = p & 7, n16 = (p >> 3) & 15, q = (p >> 7) & 3, t = (p >> 9) & 7, c = p >> 12;
    int k = c * 32 + q * 8 + j;
    if (remap) k = (k < 128) ? k : (k < 256) ? (k + 1) : (k == 256 ? 128 : K);
    const int n = t * 16 + n16;
    db[p] = f2h((k < K) ? Wb[(size_t)k * 128 + n] : 0.f);
}

__global__ __launch_bounds__(256) void k_pack_all(
    const float* __restrict__ Wm1, const float* __restrict__ Wm2,
    const float* __restrict__ Wn1, const float* __restrict__ Wn2,
    const float* __restrict__ We1, const float* __restrict__ Wc1,
    const float* __restrict__ Wrel, const float* __restrict__ Wc2,
    unsigned short* __restrict__ Wm1p, unsigned short* __restrict__ Wm2p,
    unsigned short* __restrict__ Wn1p, unsigned short* __restrict__ Wn2p,
    unsigned short* __restrict__ We1p, unsigned short* __restrict__ Wc1p,
    unsigned short* __restrict__ Wrelp, unsigned short* __restrict__ Wc2p)
{
    const int b = blockIdx.x;
    if (b < 144)        pack_block(Wm1, Wm1p, 273, 0, b);
    else if (b < 208)   pack_block(Wm2, Wm2p, 128, 0, b - 144);
    else if (b < 336)   pack_block(Wn1, Wn1p, 256, 0, b - 208);
    else if (b < 400)   pack_block(Wn2, Wn2p, 128, 0, b - 336);
    else if (b < 544)   pack_block(We1, We1p, 257, 1, b - 400);
    else if (b < 1056) {
        const int bb = b - 544, batch = bb >> 6;
        pack_block(Wc1 + (size_t)batch * 16384, Wc1p + (size_t)batch * 16384, 128, 0, bb & 63);
    } else if (b < 1568) {
        const int bb = b - 1056, batch = bb >> 6;
        pack_block(Wrel + (size_t)batch * 16384, Wrelp + (size_t)batch * 16384, 128, 0, bb & 63);
    } else {
        const int bb = b - 1568, r = bb >> 3;
        const int p = (bb & 7) * 256 + threadIdx.x;
        const int j = p & 7, n16 = (p >> 3) & 15, q = (p >> 7) & 3, c = (p >> 9) & 3;
        const int k = c * 32 + q * 8 + j;
        float v = (n16 < 4) ? Wc2[(size_t)r * 512 + k * 4 + n16] * 256.0f : 0.f;
        Wc2p[(size_t)r * 2048 + p] = f2h(v);
    }
}

// ============ radial norm-squared accumulation ============
__global__ __launch_bounds__(256) void k_norm(const float* __restrict__ coord,
                                              const int* __restrict__ edges,
                                              float* __restrict__ nsq)
{
    const int r = blockIdx.x;
    const int tid = threadIdx.x;
    const int* rows = edges + r * 2 * EE;
    const int* cols = rows + EE;
    float acc[16];
#pragma unroll
    for (int i = 0; i < 16; i++) acc[i] = 0.f;
    const int e0 = blockIdx.y * 1024;
    for (int e = e0 + tid; e < e0 + 1024; e += 256) {
        const float4* cr = (const float4*)(coord + (size_t)rows[e] * 12);
        const float4* cc = (const float4*)(coord + (size_t)cols[e] * 12);
        float4 a0 = cr[0], a1 = cr[1], a2 = cr[2];
        float4 b0 = cc[0], b1 = cc[1], b2 = cc[2];
        float cd[12] = { a0.x-b0.x, a0.y-b0.y, a0.z-b0.z, a0.w-b0.w,
                         a1.x-b1.x, a1.y-b1.y, a1.z-b1.z, a1.w-b1.w,
                         a2.x-b2.x, a2.y-b2.y, a2.z-b2.z, a2.w-b2.w };
#pragma unroll
        for (int c = 0; c < 4; c++)
#pragma unroll
            for (int d = 0; d < 4; d++) {
                float v = cd[c*3]*cd[d*3] + cd[c*3+1]*cd[d*3+1] + cd[c*3+2]*cd[d*3+2];
                acc[c*4+d] += v * v;
            }
    }
#pragma unroll
    for (int i = 0; i < 16; i++) {
        float v = acc[i];
        for (int off = 32; off; off >>= 1) v += __shfl_down(v, off, 64);
        if ((tid & 63) == 0) atomicAdd(&nsq[r * 16 + i], v);
    }
}

__global__ void k_invnorm(const float* __restrict__ nsq, float* __restrict__ inv_norm)
{
    int i = threadIdx.x;
    if (i < RR * 16) {
        float n = sqrtf(nsq[i]);
        inv_norm[i] = 1.0f / fmaxf(n, 1e-12f);
    }
}

// ============ message MLP + phi + scatters (64 edges, 256 threads) ============
// R3 double-buffer structure; shX/shCd replaced by register fragments + recompute.
__global__ __launch_bounds__(256, 2) void k_msg(
    const unsigned short* __restrict__ h_bf, const float* __restrict__ coord,
    const float* __restrict__ eattr, const int* __restrict__ edges,
    const float* __restrict__ inv_norm,
    const unsigned short* __restrict__ Wm1p, const float* __restrict__ bm1,
    const unsigned short* __restrict__ Wm2p, const float* __restrict__ bm2,
    const unsigned short* __restrict__ Wc1p, const float* __restrict__ bc1,
    const unsigned short* __restrict__ Wc2p,
    float* __restrict__ sAccum, float* __restrict__ cnt,
    unsigned short* __restrict__ seg)
{
    __shared__ __align__(16) unsigned short shT[64 * 136];  // t1, later hid
    __shared__ __align__(16) unsigned short shE[64 * 136];  // ef
    __shared__ float shPhi[64 * 4];
    __shared__ int shRow[64], shCol[64];
    __shared__ float shInv[16];

    const int tid = threadIdx.x;
    const int lane = tid & 63, wid = tid >> 6;
    const int n16 = lane & 15, q = lane >> 4;
    const int ko = q * 8;
    const int r = blockIdx.y;
    const int e0 = blockIdx.x * 64;

    if (tid < 64) shRow[tid] = edges[r * 2 * EE + e0 + tid];
    else if (tid < 128) shCol[tid - 64] = edges[r * 2 * EE + EE + e0 + (tid - 64)];
    else if (tid < 144) shInv[tid - 128] = inv_norm[r * 16 + (tid - 128)];
    __syncthreads();

    int rowN[4], colN[4];
#pragma unroll
    for (int m = 0; m < 4; m++) {
        rowN[m] = shRow[m * 16 + n16];
        colN[m] = shCol[m * 16 + n16];
    }

    // chunk-8 A fragments (radial|eattr|pad) in registers (R5-proven pattern)
    half8 aX[4];
#pragma unroll
    for (int m = 0; m < 4; m++) aX[m] = (half8)(_Float16)0.0f;
    if (q < 2) {
        float inv[8];
#pragma unroll
        for (int j = 0; j < 8; j++) inv[j] = shInv[q * 8 + j];
#pragma unroll
        for (int m = 0; m < 4; m++) {
            const float* cr = coord + (size_t)rowN[m] * 12;
            const float* cc = coord + (size_t)colN[m] * 12;
            float cd[12];
#pragma unroll
            for (int i2 = 0; i2 < 12; i2++) cd[i2] = cr[i2] - cc[i2];
#pragma unroll
            for (int j = 0; j < 8; j++) {
                const int kk = q * 8 + j, c = kk >> 2, d = kk & 3;
                float v = cd[c*3]*cd[d*3] + cd[c*3+1]*cd[d*3+1] + cd[c*3+2]*cd[d*3+2];
                aX[m][j] = (_Float16)(v * inv[j]);
            }
        }
    } else if (q == 2) {
#pragma unroll
        for (int m = 0; m < 4; m++)
            aX[m][0] = (_Float16)eattr[(size_t)r * EE + e0 + m * 16 + n16];
    }

    // ---- layer 1: msg @ Wm1 ----
    f32x4 acc[4][2];
    zero42(acc);
#pragma unroll
    for (int c = 0; c < 4; c++) {
        half8 a[4];
#pragma unroll
        for (int m = 0; m < 4; m++)
            a[m] = *(const half8*)(h_bf + (size_t)rowN[m] * 128 + c * 32 + ko);
        mfma_chunk4(Wm1p, c, wid, q, n16, a, acc);
    }
#pragma unroll
    for (int c = 0; c < 4; c++) {
        half8 a[4];
#pragma unroll
        for (int m = 0; m < 4; m++)
            a[m] = *(const half8*)(h_bf + (size_t)colN[m] * 128 + c * 32 + ko);
        mfma_chunk4(Wm1p, c + 4, wid, q, n16, a, acc);
    }
    mfma_chunk4(Wm1p, 8, wid, q, n16, aX, acc);
    store_act4(acc, bm1, shT, n16, q, wid, true);      // t1 -> shT
    __syncthreads();

    // ---- layer 2: t1 @ Wm2 -> ef ----
    zero42(acc);
    gemm_lds4<4>(Wm2p, shT, wid, q, n16, acc);
    store_act4(acc, bm2, shE, n16, q, wid, true);      // ef -> shE
    __syncthreads();                                   // separates shT reads from hid write

    // ---- layer 3: ef @ Wc1[r] -> hid ; seg += ef ----
    zero42(acc);
    gemm_lds4<4>(Wc1p + (size_t)r * 16384, shE, wid, q, n16, acc);
    store_act4(acc, bc1 + r * 128, shT, n16, q, wid, true);  // hid -> shT
    {
        unsigned short* segr = seg + (size_t)r * NN * 128;
        for (int it = tid; it < 64 * 64; it += 256) {
            const int e = it >> 6, jj = it & 63;
            const unsigned bits = *(const unsigned*)(shE + e * 136 + jj * 2);
            seg_atomic(segr + (size_t)shRow[e] * 128 + jj * 2, bits);
        }
    }
    __syncthreads();                                   // hid complete everywhere

    // ---- phi = hid @ Wc2p[r] / 256 ; wave w covers m-tile w ----
    {
        f32x4 ap = (f32x4)0.f;
        const unsigned short* Bw = Wc2p + (size_t)r * 2048;
#pragma unroll
        for (int c = 0; c < 4; c++) {
            half8 a = *(const half8*)(shT + (wid * 16 + n16) * 136 + c * 32 + ko);
            half8 b = *(const half8*)(Bw + (size_t)(c * 4 + q) * 128 + n16 * 8);
            ap = MFMA16(a, b, ap);
        }
        if (n16 < 4) {
#pragma unroll
            for (int rr = 0; rr < 4; rr++)
                shPhi[(wid * 16 + q * 4 + rr) * 4 + n16] = ap[rr] * (1.0f / 256.0f);
        }
    }
    __syncthreads();

    // ---- scatter: sAccum += cd * phi ; cnt (cd recomputed, R5-proven) ----
    {
        const int e = tid >> 2, cc4 = tid & 3;
        const int row = shRow[e], col = shCol[e];
        const float ph = shPhi[e * 4 + cc4];
#pragma unroll
        for (int d = 0; d < 3; d++) {
            const int idx = cc4 * 3 + d;
            const float cdv = coord[(size_t)row * 12 + idx] - coord[(size_t)col * 12 + idx];
            atomicAdd(&sAccum[(size_t)row * 12 + idx], cdv * ph);
        }
        if (cc4 == 0) atomicAdd(&cnt[row], 1.0f);
    }
}

// ============ node: agg GEMM (seg@Wrel) + node MLP + coord ============
__global__ __launch_bounds__(256, 2) void k_node(
    const float* __restrict__ h, const unsigned short* __restrict__ h_bf,
    const float* __restrict__ coord,
    const unsigned short* __restrict__ seg, const float* __restrict__ sAccum,
    const float* __restrict__ cnt,
    const unsigned short* __restrict__ Wrelp,
    const unsigned short* __restrict__ Wn1p, const float* __restrict__ bn1,
    const unsigned short* __restrict__ Wn2p, const float* __restrict__ bn2,
    float* __restrict__ out, unsigned short* __restrict__ hnew_bf)
{
    __shared__ __align__(16) unsigned short shAgg[64 * 136];
    __shared__ __align__(16) unsigned short shT[64 * 136];
    const int tid = threadIdx.x;
    const int lane = tid & 63, wid = tid >> 6;
    const int n16 = lane & 15, q = lane >> 4;
    const int n0 = blockIdx.x * 64;
    const int ko = q * 8;

    int nodeA[4];
#pragma unroll
    for (int m = 0; m < 4; m++) nodeA[m] = min(n0 + m * 16 + n16, NN - 1);

    f32x4 acc[4][2];
    zero42(acc);
#pragma unroll
    for (int r = 0; r < RR; r++) {
        const unsigned short* segr = seg + (size_t)r * NN * 128;
        const unsigned short* Bp = Wrelp + (size_t)r * 16384;
#pragma unroll
        for (int c = 0; c < 4; c++) {
            half8 a[4];
#pragma unroll
            for (int m = 0; m < 4; m++)
                a[m] = *(const half8*)(segr + (size_t)nodeA[m] * 128 + c * 32 + ko);
            mfma_chunk4(Bp, c, wid, q, n16, a, acc);
        }
    }
#pragma unroll
    for (int i = 0; i < 2; i++) {
        const int n = (2 * wid + i) * 16 + n16;
#pragma unroll
        for (int m = 0; m < 4; m++)
#pragma unroll
            for (int rr = 0; rr < 4; rr++)
                shAgg[(m * 16 + q * 4 + rr) * 136 + n] = f2h(acc[m][i][rr]);
    }
    __syncthreads();

    zero42(acc);
#pragma unroll
    for (int c = 0; c < 4; c++) {
        half8 a[4];
#pragma unroll
        for (int m = 0; m < 4; m++)
            a[m] = *(const half8*)(h_bf + (size_t)nodeA[m] * 128 + c * 32 + ko);
        mfma_chunk4(Wn1p, c, wid, q, n16, a, acc);
    }
#pragma unroll
    for (int c = 4; c < 8; c++) {
        half8 a[4];
#pragma unroll
        for (int m = 0; m < 4; m++)
            a[m] = *(const half8*)(shAgg + (m * 16 + n16) * 136 + (c - 4) * 32 + ko);
        mfma_chunk4(Wn1p, c, wid, q, n16, a, acc);
    }
#pragma unroll
    for (int i = 0; i < 2; i++) {
        const int n = (2 * wid + i) * 16 + n16;
        const float bb = bn1[n];
#pragma unroll
        for (int m = 0; m < 4; m++)
#pragma unroll
            for (int rr = 0; rr < 4; rr++)
                shT[(m * 16 + q * 4 + rr) * 136 + n] = f2h(silu_f(acc[m][i][rr] + bb));
    }
    __syncthreads();

    zero42(acc);
    gemm_lds4<4>(Wn2p, shT, wid, q, n16, acc);
#pragma unroll
    for (int i = 0; i < 2; i++) {
        const int n = (2 * wid + i) * 16 + n16;
        const float bb = bn2[n];
#pragma unroll
        for (int m = 0; m < 4; m++)
#pragma unroll
            for (int rr = 0; rr < 4; rr++) {
                const int node = n0 + m * 16 + q * 4 + rr;
                if (node < NN) {
                    const float v = h[(size_t)node * 128 + n] + acc[m][i][rr] + bb;
                    out[(size_t)node * 128 + n] = v;
                    hnew_bf[(size_t)node * 128 + n] = f2h(v);
                }
            }
    }
    if (tid < 64) {
        const int node = n0 + tid;
        if (node < NN) {
            const float ic = 1.0f / fmaxf(cnt[node], 1.0f);
#pragma unroll
            for (int j2 = 0; j2 < 12; j2++)
                out[OUT_X + (size_t)node * 12 + j2] =
                    coord[(size_t)node * 12 + j2] + sAccum[(size_t)node * 12 + j2] * ic;
        }
    }
}

// ============ edge output m (64 edges/block, R3 verbatim) ============
__global__ __launch_bounds__(256, 2) void k_edge(
    const unsigned short* __restrict__ hnew_bf, const float* __restrict__ eattr,
    const int* __restrict__ edges,
    const unsigned short* __restrict__ We1p, const float* __restrict__ be1,
    const float* __restrict__ We2, const float* __restrict__ be2,
    float* __restrict__ mout)
{
    __shared__ __align__(16) unsigned short shX[64 * 40];
    __shared__ __align__(16) unsigned short shT[64 * 136];
    __shared__ float shW[128];
    __shared__ int shRow[64], shCol[64];
    const int tid = threadIdx.x;
    const int lane = tid & 63, wid = tid >> 6;
    const int n16 = lane & 15, q = lane >> 4;
    const int r = blockIdx.y;
    const int e0 = blockIdx.x * 64;
    const int ko = q * 8;

    if (tid < 64) shRow[tid] = edges[r * 2 * EE + e0 + tid];
    else if (tid < 128) shCol[tid - 64] = edges[r * 2 * EE + EE + e0 + (tid - 64)];
    else shW[tid - 128] = We2[tid - 128];
    __syncthreads();

    if (tid < 64) {
        shX[tid * 40] = f2h(eattr[(size_t)r * EE + e0 + tid]);
#pragma unroll
        for (int k2 = 1; k2 < 32; k2++) shX[tid * 40 + k2] = 0;
    }
    int rowN[4], colN[4];
#pragma unroll
    for (int m = 0; m < 4; m++) {
        rowN[m] = shRow[m * 16 + n16];
        colN[m] = shCol[m * 16 + n16];
    }
    __syncthreads();

    f32x4 acc[4][2];
    zero42(acc);
#pragma unroll
    for (int c = 0; c < 4; c++) {
        half8 a[4];
#pragma unroll
        for (int m = 0; m < 4; m++)
            a[m] = *(const half8*)(hnew_bf + (size_t)rowN[m] * 128 + c * 32 + ko);
        mfma_chunk4(We1p, c, wid, q, n16, a, acc);
    }
#pragma unroll
    for (int c = 0; c < 4; c++) {
        half8 a[4];
#pragma unroll
        for (int m = 0; m < 4; m++)
            a[m] = *(const half8*)(hnew_bf + (size_t)colN[m] * 128 + c * 32 + ko);
        mfma_chunk4(We1p, c + 4, wid, q, n16, a, acc);
    }
    {
        half8 a[4];
#pragma unroll
        for (int m = 0; m < 4; m++)
            a[m] = *(const half8*)(shX + (m * 16 + n16) * 40 + ko);
        mfma_chunk4(We1p, 8, wid, q, n16, a, acc);
    }
    store_act4(acc, be1, shT, n16, q, wid, true);
    __syncthreads();

    const int e = tid >> 2, qq = tid & 3;
    const unsigned short* trow = shT + e * 136 + qq * 32;
    float p = 0.f;
#pragma unroll
    for (int kk4 = 0; kk4 < 8; kk4++) {
        const float4 w4 = *(const float4*)(&shW[qq * 32 + kk4 * 4]);
        p += h2f(trow[kk4*4+0]) * w4.x + h2f(trow[kk4*4+1]) * w4.y
           + h2f(trow[kk4*4+2]) * w4.z + h2f(trow[kk4*4+3]) * w4.w;
    }
    p += __shfl_down(p, 2, 4);
    p += __shfl_down(p, 1, 4);
    if (qq == 0) mout[(size_t)r * EE + e0 + e] = p + be2[0];
}

extern "C" void kernel_launch(void* const* d_in, const int* in_sizes, int n_in,
                              void* d_out, int out_size, void* d_ws, size_t ws_size,
                              hipStream_t stream)
{
    const float* h     = (const float*)d_in[0];
    const float* coord = (const float*)d_in[1];
    const float* eattr = (const float*)d_in[2];
    const int*   edges = (const int*)d_in[3];
    const float* Wm1 = (const float*)d_in[4];
    const float* bm1 = (const float*)d_in[5];
    const float* Wm2 = (const float*)d_in[6];
    const float* bm2 = (const float*)d_in[7];
    const float* We1 = (const float*)d_in[8];
    const float* be1 = (const float*)d_in[9];
    const float* We2 = (const float*)d_in[10];
    const float* be2 = (const float*)d_in[11];
    const float* Wn1 = (const float*)d_in[12];
    const float* bn1 = (const float*)d_in[13];
    const float* Wn2 = (const float*)d_in[14];
    const float* bn2 = (const float*)d_in[15];
    const float* Wrel = (const float*)d_in[16];
    const float* Wc1 = (const float*)d_in[17];
    const float* bc1 = (const float*)d_in[18];
    const float* Wc2 = (const float*)d_in[19];

    float* out = (float*)d_out;
    float* ws  = (float*)d_ws;

    float* nsq      = ws;            // 128 (16/relation used)
    float* inv_norm = ws + 128;      // 128
    float* cnt      = ws + 256;      // 20000
    float* sAccum   = ws + 20256;    // 240000 -> zero region ends at 260256 f32
    unsigned short* U = (unsigned short*)(ws + 260256);
    unsigned short* seg     = U;                   // 20,480,000 (zeroed)
    unsigned short* h_bf    = U + 20480000;
    unsigned short* hnew_bf = U + 23040000;
    unsigned short* Wm1p    = U + 25600000;
    unsigned short* Wm2p    = U + 25636864;
    unsigned short* Wn1p    = U + 25653248;
    unsigned short* Wn2p    = U + 25686016;
    unsigned short* We1p    = U + 25702400;
    unsigned short* Wc1p    = U + 25739264;
    unsigned short* Wrelp   = U + 25870336;
    unsigned short* Wc2p    = U + 26001408;

    hipMemsetAsync(d_ws, 0, (size_t)260256 * 4 + (size_t)20480000 * 2, stream);

    k_cvt_h<<<2500, 256, 0, stream>>>(h, h_bf);
    k_pack_all<<<1632, 256, 0, stream>>>(Wm1, Wm2, Wn1, Wn2, We1, Wc1, Wrel, Wc2,
        Wm1p, Wm2p, Wn1p, Wn2p, We1p, Wc1p, Wrelp, Wc2p);
    k_norm<<<dim3(RR, 32), 256, 0, stream>>>(coord, edges, nsq);
    k_invnorm<<<1, 128, 0, stream>>>(nsq, inv_norm);
    k_msg<<<dim3(EE / 64, RR), 256, 0, stream>>>(h_bf, coord, eattr, edges, inv_norm,
        Wm1p, bm1, Wm2p, bm2, Wc1p, bc1, Wc2p, sAccum, cnt, seg);
    k_node<<<(NN + 63) / 64, 256, 0, stream>>>(h, h_bf, coord, seg, sAccum, cnt,
        Wrelp, Wn1p, bn1, Wn2p, bn2, out, hnew_bf);
    k_edge<<<dim3(EE / 64, RR), 256, 0, stream>>>(hnew_bf, eattr, edges,
        We1p, be1, We2, be2, out + OUT_M);
}